// Round 1
// baseline (4899.134 us; speedup 1.0000x reference)
//
#include <hip/hip_runtime.h>
#include <math.h>

#define S 1024
#define D 64
#define NBH 64
#define NBINS 65536
#define EPS 1e-5f

__device__ __forceinline__ unsigned sortable(float f) {
    unsigned u = __float_as_uint(f);
    return (u & 0x80000000u) ? ~u : (u | 0x80000000u);
}

// ---------------- norms: 1/(||row||+eps) for Q and K rows ----------------
// 16 lanes per row, 16 rows per 256-thread block.
__global__ __launch_bounds__(256) void norms_kernel(
    const float* __restrict__ Q, const float* __restrict__ K,
    float* __restrict__ qinv, float* __restrict__ kinv)
{
    int tid = threadIdx.x;
    int grp = tid >> 4, lane = tid & 15;
    long long rowArea = (long long)NBH * S;            // 65536 rows per tensor
    long long row = (long long)blockIdx.x * 16 + grp;
    const float* src; float* dst;
    if (row < rowArea) { src = Q; dst = qinv; }
    else               { src = K; dst = kinv; row -= rowArea; }
    float4 v = *(const float4*)(src + row * D + lane * 4);
    float s = v.x*v.x + v.y*v.y + v.z*v.z + v.w*v.w;
    s += __shfl_xor(s, 1);
    s += __shfl_xor(s, 2);
    s += __shfl_xor(s, 4);
    s += __shfl_xor(s, 8);
    if (lane == 0) dst[row] = 1.0f / (sqrtf(s) + EPS);
}

// ---------------- GEMM1: keys = sortable(cos_sim), histogram over hi16 ----------------
// 64x64 tile per 256-thread block, 4x4 per thread, fp32.
__global__ __launch_bounds__(256) void gemm1_kernel(
    const float* __restrict__ Q, const float* __restrict__ K,
    const float* __restrict__ qinv, const float* __restrict__ kinv,
    unsigned* __restrict__ keys, unsigned* __restrict__ hist, int bh0)
{
    __shared__ float Qs[64 * 68];   // [q][d], pitch 68 (bank spread, 16B aligned)
    __shared__ float Kt[64 * 72];   // [d][k] transposed, pitch 72
    int tile = blockIdx.x & 255;
    int bhl  = blockIdx.x >> 8;
    int bh   = bh0 + bhl;
    int q0 = (tile >> 4) * 64, k0 = (tile & 15) * 64;
    int tid = threadIdx.x;

    const float* Qb = Q + ((size_t)bh * S + q0) * D;
    const float* Kb = K + ((size_t)bh * S + k0) * D;
    #pragma unroll
    for (int r = 0; r < 4; r++) {
        int f = tid + r * 256;
        int row = f >> 4, c4 = f & 15;
        float4 v = *(const float4*)(Qb + row * D + c4 * 4);
        *(float4*)(&Qs[row * 68 + c4 * 4]) = v;
        float4 w = *(const float4*)(Kb + row * D + c4 * 4);
        Kt[(c4*4+0) * 72 + row] = w.x;
        Kt[(c4*4+1) * 72 + row] = w.y;
        Kt[(c4*4+2) * 72 + row] = w.z;
        Kt[(c4*4+3) * 72 + row] = w.w;
    }
    __syncthreads();

    int tx = tid & 15, ty = tid >> 4;
    float acc[4][4] = {};
    #pragma unroll
    for (int d0 = 0; d0 < 16; d0++) {
        float4 b0 = *(const float4*)(&Kt[(d0*4+0)*72 + tx*4]);
        float4 b1 = *(const float4*)(&Kt[(d0*4+1)*72 + tx*4]);
        float4 b2 = *(const float4*)(&Kt[(d0*4+2)*72 + tx*4]);
        float4 b3 = *(const float4*)(&Kt[(d0*4+3)*72 + tx*4]);
        #pragma unroll
        for (int i = 0; i < 4; i++) {
            float4 a = *(const float4*)(&Qs[(ty*4+i)*68 + d0*4]);
            acc[i][0] += a.x*b0.x + a.y*b1.x + a.z*b2.x + a.w*b3.x;
            acc[i][1] += a.x*b0.y + a.y*b1.y + a.z*b2.y + a.w*b3.y;
            acc[i][2] += a.x*b0.z + a.y*b1.z + a.z*b2.z + a.w*b3.z;
            acc[i][3] += a.x*b0.w + a.y*b1.w + a.z*b2.w + a.w*b3.w;
        }
    }

    float kj[4];
    #pragma unroll
    for (int j = 0; j < 4; j++) kj[j] = kinv[(size_t)bh * S + k0 + tx*4 + j];
    unsigned* hb = hist + (size_t)bhl * NBINS;
    #pragma unroll
    for (int i = 0; i < 4; i++) {
        float qi = qinv[(size_t)bh * S + q0 + ty*4 + i];
        uint4 kv;
        kv.x = sortable(acc[i][0] * qi * kj[0]);
        kv.y = sortable(acc[i][1] * qi * kj[1]);
        kv.z = sortable(acc[i][2] * qi * kj[2]);
        kv.w = sortable(acc[i][3] * qi * kj[3]);
        *(uint4*)(keys + ((size_t)bhl * S + q0 + ty*4 + i) * S + k0 + tx*4) = kv;
        atomicAdd(&hb[kv.x >> 16], 1u);
        atomicAdd(&hb[kv.y >> 16], 1u);
        atomicAdd(&hb[kv.z >> 16], 1u);
        atomicAdd(&hb[kv.w >> 16], 1u);
    }
}

// ---------------- weight table: suffix scan of hist + lgamma bin-average weight ----------------
// one 1024-thread block per bh; overwrites hist (uint counts) with float weights.
__global__ __launch_bounds__(1024) void table_kernel(unsigned* __restrict__ hist)
{
    __shared__ unsigned s[1024];
    int tid = threadIdx.x;
    unsigned* h = hist + (size_t)blockIdx.x * NBINS;
    float* wt = (float*)h;
    unsigned running = 0;
    const double ln_n = 13.862943611198906; // ln(1048576)
    for (int cc = 63; cc >= 0; cc--) {
        int i = cc * 1024 + tid;
        unsigned c = h[i];
        s[tid] = c;
        __syncthreads();
        for (int ofs = 1; ofs < 1024; ofs <<= 1) {
            unsigned v = s[tid] + ((tid + ofs < 1024) ? s[tid + ofs] : 0u);
            __syncthreads();
            s[tid] = v;
            __syncthreads();
        }
        unsigned base = running + (s[tid] - c);     // elements in strictly-higher bins
        unsigned total = s[0];
        __syncthreads();                            // protect s before next iteration
        float w = 0.0f;
        if (c > 0) {
            double b = (double)base, e = (double)(base + c);
            double val = (double)c * ln_n - (lgamma(e + 1.0) - lgamma(b + 1.0));
            w = (float)(val / (double)c);
        }
        wt[i] = w;
        running += total;
    }
}

// ---------------- GEMM2: out = (W/rowsum) @ V, rowsum fused ----------------
// block = 64 q-rows x full 64 d cols; gathers weights from table.
__global__ __launch_bounds__(256) void gemm2_kernel(
    const unsigned* __restrict__ keys, const float* __restrict__ Wtab,
    const float* __restrict__ V, float* __restrict__ out, int bh0)
{
    __shared__ float Ws[64 * 68];   // [q][k] weights
    __shared__ float Vs[64 * 68];   // [k][d]
    __shared__ float rowsum[64];
    int bhl = blockIdx.x >> 4;
    int bh  = bh0 + bhl;
    int q0  = (blockIdx.x & 15) * 64;
    int tid = threadIdx.x;
    int tx = tid & 15, ty = tid >> 4;

    const unsigned* kb = keys + ((size_t)bhl * S + q0) * S;
    const float* wt = Wtab + (size_t)bhl * NBINS;
    const float* Vb = V + (size_t)bh * S * D;

    float acc[4][4] = {};
    float rs[4] = {0.f, 0.f, 0.f, 0.f};

    for (int kk = 0; kk < S; kk += 64) {
        #pragma unroll
        for (int r = 0; r < 4; r++) {
            int f = tid + r * 256;
            int row = f >> 4, c4 = f & 15;
            *(float4*)(&Vs[row*68 + c4*4]) = *(const float4*)(Vb + (size_t)(kk + row) * D + c4*4);
            uint4 kv = *(const uint4*)(kb + (size_t)row * S + kk + c4*4);
            float w0 = wt[kv.x >> 16], w1 = wt[kv.y >> 16];
            float w2 = wt[kv.z >> 16], w3 = wt[kv.w >> 16];
            float4 wv; wv.x = w0; wv.y = w1; wv.z = w2; wv.w = w3;
            *(float4*)(&Ws[row*68 + c4*4]) = wv;
            rs[r] += w0 + w1 + w2 + w3;
        }
        __syncthreads();
        #pragma unroll
        for (int j4 = 0; j4 < 16; j4++) {
            float4 b0 = *(const float4*)(&Vs[(j4*4+0)*68 + tx*4]);
            float4 b1 = *(const float4*)(&Vs[(j4*4+1)*68 + tx*4]);
            float4 b2 = *(const float4*)(&Vs[(j4*4+2)*68 + tx*4]);
            float4 b3 = *(const float4*)(&Vs[(j4*4+3)*68 + tx*4]);
            #pragma unroll
            for (int i = 0; i < 4; i++) {
                float4 a = *(const float4*)(&Ws[(ty*4+i)*68 + j4*4]);
                acc[i][0] += a.x*b0.x + a.y*b1.x + a.z*b2.x + a.w*b3.x;
                acc[i][1] += a.x*b0.y + a.y*b1.y + a.z*b2.y + a.w*b3.y;
                acc[i][2] += a.x*b0.z + a.y*b1.z + a.z*b2.z + a.w*b3.z;
                acc[i][3] += a.x*b0.w + a.y*b1.w + a.z*b2.w + a.w*b3.w;
            }
        }
        __syncthreads();
    }

    // rowsum: rs[r] belongs to local row r*16+ty; reduce across the 16 tx lanes
    #pragma unroll
    for (int r = 0; r < 4; r++) {
        float v = rs[r];
        v += __shfl_xor(v, 1);
        v += __shfl_xor(v, 2);
        v += __shfl_xor(v, 4);
        v += __shfl_xor(v, 8);
        if (tx == 0) rowsum[r*16 + ty] = v;
    }
    __syncthreads();

    #pragma unroll
    for (int i = 0; i < 4; i++) {
        float inv = 1.0f / rowsum[ty*4 + i];
        float4 o;
        o.x = acc[i][0] * inv; o.y = acc[i][1] * inv;
        o.z = acc[i][2] * inv; o.w = acc[i][3] * inv;
        *(float4*)(out + ((size_t)bh * S + q0 + ty*4 + i) * D + tx*4) = o;
    }
}

extern "C" void kernel_launch(void* const* d_in, const int* in_sizes, int n_in,
                              void* d_out, int out_size, void* d_ws, size_t ws_size,
                              hipStream_t stream) {
    const float* Q = (const float*)d_in[0];
    const float* K = (const float*)d_in[1];
    const float* V = (const float*)d_in[2];
    float* out = (float*)d_out;

    char* w = (char*)d_ws;
    float* qinv = (float*)w;
    float* kinv = qinv + NBH * S;
    size_t off = (size_t)2 * NBH * S * sizeof(float);          // 512 KB
    size_t per_bh = (size_t)NBINS * 4 + (size_t)S * S * 4;     // hist + keys per bh
    long long avail = (long long)ws_size - (long long)off;
    int G = (int)(avail / (long long)per_bh);
    if (G > NBH) G = NBH;
    if (G < 1) G = 1;
    unsigned* hist = (unsigned*)(w + off);
    unsigned* keys = (unsigned*)(w + off + (size_t)G * NBINS * 4);

    norms_kernel<<<(2 * NBH * S) / 16, 256, 0, stream>>>(Q, K, qinv, kinv);

    for (int bh0 = 0; bh0 < NBH; bh0 += G) {
        int Gc = (NBH - bh0 < G) ? (NBH - bh0) : G;
        hipMemsetAsync(hist, 0, (size_t)Gc * NBINS * 4, stream);
        gemm1_kernel<<<Gc * 256, 256, 0, stream>>>(Q, K, qinv, kinv, keys, hist, bh0);
        table_kernel<<<Gc, 1024, 0, stream>>>(hist);
        gemm2_kernel<<<Gc * 16, 256, 0, stream>>>(keys, (const float*)hist, V, out, bh0);
    }
}

// Round 2
// 864.482 us; speedup vs baseline: 5.6671x; 5.6671x over previous
//
#include <hip/hip_runtime.h>
#include <math.h>

#define S 1024
#define D 64
#define NBH 64
#define NBINS 8192
#define EPS 1e-5f

__device__ __forceinline__ int binof(float sim) {
    int b = (int)((sim + 1.0f) * (NBINS / 2));
    return b < 0 ? 0 : (b > NBINS - 1 ? NBINS - 1 : b);
}

// ---------------- norms: 1/(||row||+eps) for Q and K rows ----------------
__global__ __launch_bounds__(256) void norms_kernel(
    const float* __restrict__ Q, const float* __restrict__ K,
    float* __restrict__ qinv, float* __restrict__ kinv)
{
    int tid = threadIdx.x;
    int grp = tid >> 4, lane = tid & 15;
    long long rowArea = (long long)NBH * S;
    long long row = (long long)blockIdx.x * 16 + grp;
    const float* src; float* dst;
    if (row < rowArea) { src = Q; dst = qinv; }
    else               { src = K; dst = kinv; row -= rowArea; }
    float4 v = *(const float4*)(src + row * D + lane * 4);
    float s = v.x*v.x + v.y*v.y + v.z*v.z + v.w*v.w;
    s += __shfl_xor(s, 1);
    s += __shfl_xor(s, 2);
    s += __shfl_xor(s, 4);
    s += __shfl_xor(s, 8);
    if (lane == 0) dst[row] = 1.0f / (sqrtf(s) + EPS);
}

// ---------------- GEMM1: u16 bin keys + LDS-privatized histogram ----------------
__global__ __launch_bounds__(256) void gemm1_kernel(
    const float* __restrict__ Q, const float* __restrict__ K,
    const float* __restrict__ qinv, const float* __restrict__ kinv,
    unsigned short* __restrict__ keys, unsigned* __restrict__ hist, int bh0)
{
    __shared__ float Qs[64 * 68];        // 17.4 KB
    __shared__ float Kt[64 * 72];        // 18.4 KB
    __shared__ unsigned hist_s[NBINS];   // 32 KB
    int tile = blockIdx.x & 255;
    int bhl  = blockIdx.x >> 8;
    int bh   = bh0 + bhl;
    int q0 = (tile >> 4) * 64, k0 = (tile & 15) * 64;
    int tid = threadIdx.x;

    #pragma unroll
    for (int i = tid; i < NBINS; i += 256) hist_s[i] = 0;

    const float* Qb = Q + ((size_t)bh * S + q0) * D;
    const float* Kb = K + ((size_t)bh * S + k0) * D;
    #pragma unroll
    for (int r = 0; r < 4; r++) {
        int f = tid + r * 256;
        int row = f >> 4, c4 = f & 15;
        float4 v = *(const float4*)(Qb + row * D + c4 * 4);
        *(float4*)(&Qs[row * 68 + c4 * 4]) = v;
        float4 w = *(const float4*)(Kb + row * D + c4 * 4);
        Kt[(c4*4+0) * 72 + row] = w.x;
        Kt[(c4*4+1) * 72 + row] = w.y;
        Kt[(c4*4+2) * 72 + row] = w.z;
        Kt[(c4*4+3) * 72 + row] = w.w;
    }
    __syncthreads();

    int tx = tid & 15, ty = tid >> 4;
    float acc[4][4] = {};
    #pragma unroll
    for (int d0 = 0; d0 < 16; d0++) {
        float4 b0 = *(const float4*)(&Kt[(d0*4+0)*72 + tx*4]);
        float4 b1 = *(const float4*)(&Kt[(d0*4+1)*72 + tx*4]);
        float4 b2 = *(const float4*)(&Kt[(d0*4+2)*72 + tx*4]);
        float4 b3 = *(const float4*)(&Kt[(d0*4+3)*72 + tx*4]);
        #pragma unroll
        for (int i = 0; i < 4; i++) {
            float4 a = *(const float4*)(&Qs[(ty*4+i)*68 + d0*4]);
            acc[i][0] += a.x*b0.x + a.y*b1.x + a.z*b2.x + a.w*b3.x;
            acc[i][1] += a.x*b0.y + a.y*b1.y + a.z*b2.y + a.w*b3.y;
            acc[i][2] += a.x*b0.z + a.y*b1.z + a.z*b2.z + a.w*b3.z;
            acc[i][3] += a.x*b0.w + a.y*b1.w + a.z*b2.w + a.w*b3.w;
        }
    }

    float kj[4];
    #pragma unroll
    for (int j = 0; j < 4; j++) kj[j] = kinv[(size_t)bh * S + k0 + tx*4 + j];
    #pragma unroll
    for (int i = 0; i < 4; i++) {
        float qi = qinv[(size_t)bh * S + q0 + ty*4 + i];
        int b0 = binof(acc[i][0] * qi * kj[0]);
        int b1 = binof(acc[i][1] * qi * kj[1]);
        int b2 = binof(acc[i][2] * qi * kj[2]);
        int b3 = binof(acc[i][3] * qi * kj[3]);
        ushort4 kv;
        kv.x = (unsigned short)b0; kv.y = (unsigned short)b1;
        kv.z = (unsigned short)b2; kv.w = (unsigned short)b3;
        *(ushort4*)(keys + ((size_t)bhl * S + q0 + ty*4 + i) * S + k0 + tx*4) = kv;
        atomicAdd(&hist_s[b0], 1u);
        atomicAdd(&hist_s[b1], 1u);
        atomicAdd(&hist_s[b2], 1u);
        atomicAdd(&hist_s[b3], 1u);
    }
    __syncthreads();

    unsigned* hb = hist + (size_t)bhl * NBINS;
    #pragma unroll
    for (int i = tid; i < NBINS; i += 256) {
        unsigned c = hist_s[i];
        if (c) atomicAdd(&hb[i], c);
    }
}

// ---------------- weight table: suffix scan + lgamma bin-average weight ----------------
__global__ __launch_bounds__(1024) void table_kernel(unsigned* __restrict__ hist)
{
    __shared__ unsigned s[1024];
    int tid = threadIdx.x;
    unsigned* h = hist + (size_t)blockIdx.x * NBINS;
    float* wt = (float*)h;
    unsigned running = 0;
    const double ln_n = 13.862943611198906; // ln(1048576)
    for (int cc = NBINS / 1024 - 1; cc >= 0; cc--) {
        int i = cc * 1024 + tid;
        unsigned c = h[i];
        s[tid] = c;
        __syncthreads();
        for (int ofs = 1; ofs < 1024; ofs <<= 1) {
            unsigned v = s[tid] + ((tid + ofs < 1024) ? s[tid + ofs] : 0u);
            __syncthreads();
            s[tid] = v;
            __syncthreads();
        }
        unsigned base = running + (s[tid] - c);
        unsigned total = s[0];
        __syncthreads();
        float w = 0.0f;
        if (c > 0) {
            double b = (double)base, e = (double)(base + c);
            double val = (double)c * ln_n - (lgamma(e + 1.0) - lgamma(b + 1.0));
            w = (float)(val / (double)c);
        }
        wt[i] = w;
        running += total;
    }
}

// ---------------- GEMM2: out = (W/rowsum) @ V, weight table staged in LDS ----------------
__global__ __launch_bounds__(256) void gemm2_kernel(
    const unsigned short* __restrict__ keys, const float* __restrict__ Wtab,
    const float* __restrict__ V, float* __restrict__ out, int bh0)
{
    __shared__ float wt_s[NBINS];     // 32 KB
    __shared__ float Ws[64 * 68];
    __shared__ float Vs[64 * 68];
    __shared__ float rowsum[64];
    int bhl = blockIdx.x >> 4;
    int bh  = bh0 + bhl;
    int q0  = (blockIdx.x & 15) * 64;
    int tid = threadIdx.x;
    int tx = tid & 15, ty = tid >> 4;

    const float* wt = Wtab + (size_t)bhl * NBINS;
    #pragma unroll
    for (int i = tid; i < NBINS / 4; i += 256)
        ((float4*)wt_s)[i] = ((const float4*)wt)[i];
    __syncthreads();

    const unsigned short* kb = keys + ((size_t)bhl * S + q0) * S;
    const float* Vb = V + (size_t)bh * S * D;

    float acc[4][4] = {};
    float rs[4] = {0.f, 0.f, 0.f, 0.f};

    for (int kk = 0; kk < S; kk += 64) {
        #pragma unroll
        for (int r = 0; r < 4; r++) {
            int f = tid + r * 256;
            int row = f >> 4, c4 = f & 15;
            *(float4*)(&Vs[row*68 + c4*4]) = *(const float4*)(Vb + (size_t)(kk + row) * D + c4*4);
            ushort4 kv = *(const ushort4*)(kb + (size_t)row * S + kk + c4*4);
            float w0 = wt_s[kv.x], w1 = wt_s[kv.y];
            float w2 = wt_s[kv.z], w3 = wt_s[kv.w];
            float4 wv; wv.x = w0; wv.y = w1; wv.z = w2; wv.w = w3;
            *(float4*)(&Ws[row*68 + c4*4]) = wv;
            rs[r] += w0 + w1 + w2 + w3;
        }
        __syncthreads();
        #pragma unroll
        for (int j4 = 0; j4 < 16; j4++) {
            float4 b0 = *(const float4*)(&Vs[(j4*4+0)*68 + tx*4]);
            float4 b1 = *(const float4*)(&Vs[(j4*4+1)*68 + tx*4]);
            float4 b2 = *(const float4*)(&Vs[(j4*4+2)*68 + tx*4]);
            float4 b3 = *(const float4*)(&Vs[(j4*4+3)*68 + tx*4]);
            #pragma unroll
            for (int i = 0; i < 4; i++) {
                float4 a = *(const float4*)(&Ws[(ty*4+i)*68 + j4*4]);
                acc[i][0] += a.x*b0.x + a.y*b1.x + a.z*b2.x + a.w*b3.x;
                acc[i][1] += a.x*b0.y + a.y*b1.y + a.z*b2.y + a.w*b3.y;
                acc[i][2] += a.x*b0.z + a.y*b1.z + a.z*b2.z + a.w*b3.z;
                acc[i][3] += a.x*b0.w + a.y*b1.w + a.z*b2.w + a.w*b3.w;
            }
        }
        __syncthreads();
    }

    #pragma unroll
    for (int r = 0; r < 4; r++) {
        float v = rs[r];
        v += __shfl_xor(v, 1);
        v += __shfl_xor(v, 2);
        v += __shfl_xor(v, 4);
        v += __shfl_xor(v, 8);
        if (tx == 0) rowsum[r*16 + ty] = v;
    }
    __syncthreads();

    #pragma unroll
    for (int i = 0; i < 4; i++) {
        float inv = 1.0f / rowsum[ty*4 + i];
        float4 o;
        o.x = acc[i][0] * inv; o.y = acc[i][1] * inv;
        o.z = acc[i][2] * inv; o.w = acc[i][3] * inv;
        *(float4*)(out + ((size_t)bh * S + q0 + ty*4 + i) * D + tx*4) = o;
    }
}

extern "C" void kernel_launch(void* const* d_in, const int* in_sizes, int n_in,
                              void* d_out, int out_size, void* d_ws, size_t ws_size,
                              hipStream_t stream) {
    const float* Q = (const float*)d_in[0];
    const float* K = (const float*)d_in[1];
    const float* V = (const float*)d_in[2];
    float* out = (float*)d_out;

    char* w = (char*)d_ws;
    float* qinv = (float*)w;
    float* kinv = qinv + NBH * S;
    size_t off = (size_t)2 * NBH * S * sizeof(float);
    size_t per_bh = (size_t)NBINS * 4 + (size_t)S * S * 2;   // hist + u16 keys
    long long avail = (long long)ws_size - (long long)off;
    int G = (int)(avail / (long long)per_bh);
    if (G > NBH) G = NBH;
    if (G < 1) G = 1;
    unsigned* hist = (unsigned*)(w + off);
    unsigned short* keys = (unsigned short*)(w + off + (size_t)G * NBINS * 4);

    norms_kernel<<<(2 * NBH * S) / 16, 256, 0, stream>>>(Q, K, qinv, kinv);

    for (int bh0 = 0; bh0 < NBH; bh0 += G) {
        int Gc = (NBH - bh0 < G) ? (NBH - bh0) : G;
        hipMemsetAsync(hist, 0, (size_t)Gc * NBINS * 4, stream);
        gemm1_kernel<<<Gc * 256, 256, 0, stream>>>(Q, K, qinv, kinv, keys, hist, bh0);
        table_kernel<<<Gc, 1024, 0, stream>>>(hist);
        gemm2_kernel<<<Gc * 16, 256, 0, stream>>>(keys, (const float*)hist, V, out, bh0);
    }
}

// Round 3
// 583.944 us; speedup vs baseline: 8.3897x; 1.4804x over previous
//
#include <hip/hip_runtime.h>
#include <math.h>

#define S 1024
#define D 64
#define NBH 64
#define NBINS 8192
#define NWORDS (NBINS / 2)
#define EPS 1e-5f

__device__ __forceinline__ int binof(float sim) {
    int b = (int)((sim + 1.0f) * (NBINS / 2));
    return b < 0 ? 0 : (b > NBINS - 1 ? NBINS - 1 : b);
}

// ---------------- norms: 1/(||row||+eps) for Q and K rows ----------------
__global__ __launch_bounds__(256) void norms_kernel(
    const float* __restrict__ Q, const float* __restrict__ K,
    float* __restrict__ qinv, float* __restrict__ kinv)
{
    int tid = threadIdx.x;
    int grp = tid >> 4, lane = tid & 15;
    long long rowArea = (long long)NBH * S;
    long long row = (long long)blockIdx.x * 16 + grp;
    const float* src; float* dst;
    if (row < rowArea) { src = Q; dst = qinv; }
    else               { src = K; dst = kinv; row -= rowArea; }
    float4 v = *(const float4*)(src + row * D + lane * 4);
    float s = v.x*v.x + v.y*v.y + v.z*v.z + v.w*v.w;
    s += __shfl_xor(s, 1);
    s += __shfl_xor(s, 2);
    s += __shfl_xor(s, 4);
    s += __shfl_xor(s, 8);
    if (lane == 0) dst[row] = 1.0f / (sqrtf(s) + EPS);
}

// ---------------- GEMM1: u16 bin keys + packed-u16 LDS histogram ----------------
// Kt swizzle: K[k][d] lives at Kt[d*64 + (k ^ ((d>>2 & 7)<<2))]
__global__ __launch_bounds__(256) void gemm1_kernel(
    const float* __restrict__ Q, const float* __restrict__ K,
    const float* __restrict__ qinv, const float* __restrict__ kinv,
    unsigned short* __restrict__ keys, unsigned* __restrict__ hist, int bh0)
{
    __shared__ float Qs[64 * 64];        // 16 KB, pitch 64 (reads broadcast)
    __shared__ float Kt[64 * 64];        // 16 KB, swizzled
    __shared__ unsigned hist_s[NWORDS];  // 16 KB packed u16 pairs
    int tile = blockIdx.x & 255;
    int bhl  = blockIdx.x >> 8;
    int bh   = bh0 + bhl;
    int q0 = (tile >> 4) * 64, k0 = (tile & 15) * 64;
    int tid = threadIdx.x;

    #pragma unroll
    for (int i = tid; i < NWORDS / 4; i += 256) ((uint4*)hist_s)[i] = make_uint4(0,0,0,0);

    const float* Qb = Q + ((size_t)bh * S + q0) * D;
    const float* Kb = K + ((size_t)bh * S + k0) * D;
    #pragma unroll
    for (int r = 0; r < 4; r++) {
        int f = tid + r * 256;
        int row = f >> 4, c4 = f & 15;
        float4 v = *(const float4*)(Qb + row * D + c4 * 4);
        *(float4*)(&Qs[row * 64 + c4 * 4]) = v;
        float4 w = *(const float4*)(Kb + row * D + c4 * 4);
        int swz = row ^ ((c4 & 7) << 2);          // (d>>2)&7 == c4
        Kt[(c4*4+0) * 64 + swz] = w.x;
        Kt[(c4*4+1) * 64 + swz] = w.y;
        Kt[(c4*4+2) * 64 + swz] = w.z;
        Kt[(c4*4+3) * 64 + swz] = w.w;
    }
    __syncthreads();

    int tx = tid & 15, ty = tid >> 4;
    float acc[4][4] = {};
    #pragma unroll
    for (int d0 = 0; d0 < 16; d0++) {
        int kbase = (tx * 4) ^ ((d0 & 7) << 2);   // float4 there = logical k = tx*4..+3
        float4 b0 = *(const float4*)(&Kt[(d0*4+0)*64 + kbase]);
        float4 b1 = *(const float4*)(&Kt[(d0*4+1)*64 + kbase]);
        float4 b2 = *(const float4*)(&Kt[(d0*4+2)*64 + kbase]);
        float4 b3 = *(const float4*)(&Kt[(d0*4+3)*64 + kbase]);
        #pragma unroll
        for (int i = 0; i < 4; i++) {
            float4 a = *(const float4*)(&Qs[(ty*4+i)*64 + d0*4]);
            acc[i][0] += a.x*b0.x + a.y*b1.x + a.z*b2.x + a.w*b3.x;
            acc[i][1] += a.x*b0.y + a.y*b1.y + a.z*b2.y + a.w*b3.y;
            acc[i][2] += a.x*b0.z + a.y*b1.z + a.z*b2.z + a.w*b3.z;
            acc[i][3] += a.x*b0.w + a.y*b1.w + a.z*b2.w + a.w*b3.w;
        }
    }

    float kj[4];
    #pragma unroll
    for (int j = 0; j < 4; j++) kj[j] = kinv[(size_t)bh * S + k0 + tx*4 + j];
    #pragma unroll
    for (int i = 0; i < 4; i++) {
        float qi = qinv[(size_t)bh * S + q0 + ty*4 + i];
        int b0 = binof(acc[i][0] * qi * kj[0]);
        int b1 = binof(acc[i][1] * qi * kj[1]);
        int b2 = binof(acc[i][2] * qi * kj[2]);
        int b3 = binof(acc[i][3] * qi * kj[3]);
        ushort4 kv;
        kv.x = (unsigned short)b0; kv.y = (unsigned short)b1;
        kv.z = (unsigned short)b2; kv.w = (unsigned short)b3;
        *(ushort4*)(keys + ((size_t)bhl * S + q0 + ty*4 + i) * S + k0 + tx*4) = kv;
        atomicAdd(&hist_s[b0 >> 1], 1u << ((b0 & 1) << 4));
        atomicAdd(&hist_s[b1 >> 1], 1u << ((b1 & 1) << 4));
        atomicAdd(&hist_s[b2 >> 1], 1u << ((b2 & 1) << 4));
        atomicAdd(&hist_s[b3 >> 1], 1u << ((b3 & 1) << 4));
    }
    __syncthreads();

    unsigned* hb = hist + (size_t)bhl * NWORDS;
    #pragma unroll
    for (int i = tid; i < NWORDS; i += 256) {
        unsigned v = hist_s[i];
        if (v) atomicAdd(&hb[i], v);   // packed u16 pair add; per-bh totals << 65536
    }
}

// ---------------- weight table: unpack + suffix scan + lgamma bin-average ----------------
// 1024 threads/block, one block per bh. 8 bins (4 packed words) per thread.
__global__ __launch_bounds__(1024) void table_kernel(
    const unsigned* __restrict__ hist, float* __restrict__ wtab)
{
    __shared__ unsigned ssum[1024];
    int tid = threadIdx.x;
    const unsigned* h = hist + (size_t)blockIdx.x * NWORDS;
    float* wt = wtab + (size_t)blockIdx.x * NBINS;

    unsigned c[8];
    unsigned tot = 0;
    #pragma unroll
    for (int j = 0; j < 4; j++) {
        unsigned w = h[tid * 4 + j];
        c[2*j]   = w & 0xffffu;
        c[2*j+1] = w >> 16;
        tot += c[2*j] + c[2*j+1];
    }
    ssum[tid] = tot;
    __syncthreads();
    for (int ofs = 1; ofs < 1024; ofs <<= 1) {
        unsigned v = ssum[tid] + ((tid + ofs < 1024) ? ssum[tid + ofs] : 0u);
        __syncthreads();
        ssum[tid] = v;
        __syncthreads();
    }
    unsigned run = (tid < 1023) ? ssum[tid + 1] : 0u;   // elems in bins of higher threads

    const double ln_n = 13.862943611198906; // ln(1048576)
    #pragma unroll
    for (int i = 7; i >= 0; i--) {
        unsigned ci = c[i];
        float w = 0.0f;
        if (ci) {
            double b = (double)run, e = (double)(run + ci);
            double val = (double)ci * ln_n - (lgamma(e + 1.0) - lgamma(b + 1.0));
            w = (float)(val / (double)ci);
        }
        wt[tid * 8 + i] = w;
        run += ci;
    }
}

// ---------------- GEMM2: out = (W/rowsum) @ V, weight table staged in LDS ----------------
__global__ __launch_bounds__(256) void gemm2_kernel(
    const unsigned short* __restrict__ keys, const float* __restrict__ Wtab,
    const float* __restrict__ V, float* __restrict__ out, int bh0)
{
    __shared__ float wt_s[NBINS];     // 32 KB
    __shared__ float Ws[64 * 64];     // 16 KB
    __shared__ float Vs[64 * 64];     // 16 KB
    __shared__ float rowsum[64];
    int bhl = blockIdx.x >> 4;
    int bh  = bh0 + bhl;
    int q0  = (blockIdx.x & 15) * 64;
    int tid = threadIdx.x;
    int tx = tid & 15, ty = tid >> 4;

    const float* wt = Wtab + (size_t)bhl * NBINS;
    #pragma unroll
    for (int i = tid; i < NBINS / 4; i += 256)
        ((float4*)wt_s)[i] = ((const float4*)wt)[i];
    __syncthreads();

    const unsigned short* kb = keys + ((size_t)bhl * S + q0) * S;
    const float* Vb = V + (size_t)bh * S * D;

    float acc[4][4] = {};
    float rs[4] = {0.f, 0.f, 0.f, 0.f};

    for (int kk = 0; kk < S; kk += 64) {
        #pragma unroll
        for (int r = 0; r < 4; r++) {
            int f = tid + r * 256;
            int row = f >> 4, c4 = f & 15;
            *(float4*)(&Vs[row*64 + c4*4]) = *(const float4*)(Vb + (size_t)(kk + row) * D + c4*4);
            ushort4 kv = *(const ushort4*)(kb + (size_t)row * S + kk + c4*4);
            float w0 = wt_s[kv.x], w1 = wt_s[kv.y];
            float w2 = wt_s[kv.z], w3 = wt_s[kv.w];
            float4 wv; wv.x = w0; wv.y = w1; wv.z = w2; wv.w = w3;
            *(float4*)(&Ws[row*64 + c4*4]) = wv;
            rs[r] += w0 + w1 + w2 + w3;
        }
        __syncthreads();
        #pragma unroll
        for (int j4 = 0; j4 < 16; j4++) {
            float4 b0 = *(const float4*)(&Vs[(j4*4+0)*64 + tx*4]);
            float4 b1 = *(const float4*)(&Vs[(j4*4+1)*64 + tx*4]);
            float4 b2 = *(const float4*)(&Vs[(j4*4+2)*64 + tx*4]);
            float4 b3 = *(const float4*)(&Vs[(j4*4+3)*64 + tx*4]);
            #pragma unroll
            for (int i = 0; i < 4; i++) {
                float4 a = *(const float4*)(&Ws[(ty*4+i)*64 + j4*4]);
                acc[i][0] += a.x*b0.x + a.y*b1.x + a.z*b2.x + a.w*b3.x;
                acc[i][1] += a.x*b0.y + a.y*b1.y + a.z*b2.y + a.w*b3.y;
                acc[i][2] += a.x*b0.z + a.y*b1.z + a.z*b2.z + a.w*b3.z;
                acc[i][3] += a.x*b0.w + a.y*b1.w + a.z*b2.w + a.w*b3.w;
            }
        }
        __syncthreads();
    }

    #pragma unroll
    for (int r = 0; r < 4; r++) {
        float v = rs[r];
        v += __shfl_xor(v, 1);
        v += __shfl_xor(v, 2);
        v += __shfl_xor(v, 4);
        v += __shfl_xor(v, 8);
        if (tx == 0) rowsum[r*16 + ty] = v;
    }
    __syncthreads();

    #pragma unroll
    for (int i = 0; i < 4; i++) {
        float inv = 1.0f / rowsum[ty*4 + i];
        float4 o;
        o.x = acc[i][0] * inv; o.y = acc[i][1] * inv;
        o.z = acc[i][2] * inv; o.w = acc[i][3] * inv;
        *(float4*)(out + ((size_t)bh * S + q0 + ty*4 + i) * D + tx*4) = o;
    }
}

extern "C" void kernel_launch(void* const* d_in, const int* in_sizes, int n_in,
                              void* d_out, int out_size, void* d_ws, size_t ws_size,
                              hipStream_t stream) {
    const float* Q = (const float*)d_in[0];
    const float* K = (const float*)d_in[1];
    const float* V = (const float*)d_in[2];
    float* out = (float*)d_out;

    char* w = (char*)d_ws;
    float* qinv = (float*)w;
    float* kinv = qinv + NBH * S;
    size_t off = (size_t)2 * NBH * S * sizeof(float);
    // per-bh: packed hist (NWORDS u32) + weight table (NBINS f32) + u16 keys (S*S)
    size_t per_bh = (size_t)NWORDS * 4 + (size_t)NBINS * 4 + (size_t)S * S * 2;
    long long avail = (long long)ws_size - (long long)off;
    int G = (int)(avail / (long long)per_bh);
    if (G > NBH) G = NBH;
    if (G < 1) G = 1;
    unsigned* hist = (unsigned*)(w + off);
    float* wtab = (float*)(w + off + (size_t)G * NWORDS * 4);
    unsigned short* keys = (unsigned short*)(w + off + (size_t)G * NWORDS * 4 + (size_t)G * NBINS * 4);

    norms_kernel<<<(2 * NBH * S) / 16, 256, 0, stream>>>(Q, K, qinv, kinv);

    for (int bh0 = 0; bh0 < NBH; bh0 += G) {
        int Gc = (NBH - bh0 < G) ? (NBH - bh0) : G;
        hipMemsetAsync(hist, 0, (size_t)Gc * NWORDS * 4, stream);
        gemm1_kernel<<<Gc * 256, 256, 0, stream>>>(Q, K, qinv, kinv, keys, hist, bh0);
        table_kernel<<<Gc, 1024, 0, stream>>>(hist, wtab);
        gemm2_kernel<<<Gc * 16, 256, 0, stream>>>(keys, wtab, V, out, bh0);
    }
}

// Round 4
// 321.446 us; speedup vs baseline: 15.2409x; 1.8166x over previous
//
#include <hip/hip_runtime.h>
#include <math.h>

#define S 1024
#define D 64
#define NBH 64
#define NBINS 8192
#define NWORDS (NBINS / 2)
#define EPS 1e-5f

typedef __attribute__((ext_vector_type(8))) short short8;
typedef __attribute__((ext_vector_type(4))) float floatx4;

__device__ __forceinline__ int binof(float sim) {
    int b = (int)((sim + 1.0f) * (NBINS / 2));
    return b < 0 ? 0 : (b > NBINS - 1 ? NBINS - 1 : b);
}

__device__ __forceinline__ unsigned short f2bf(float f) {   // RNE f32->bf16
    unsigned u = __float_as_uint(f);
    u += 0x7fffu + ((u >> 16) & 1u);
    return (unsigned short)(u >> 16);
}

// ---------------- norms: 1/(||row||+eps) for Q and K rows ----------------
__global__ __launch_bounds__(256) void norms_kernel(
    const float* __restrict__ Q, const float* __restrict__ K,
    float* __restrict__ qinv, float* __restrict__ kinv)
{
    int tid = threadIdx.x;
    int grp = tid >> 4, lane = tid & 15;
    long long rowArea = (long long)NBH * S;
    long long row = (long long)blockIdx.x * 16 + grp;
    const float* src; float* dst;
    if (row < rowArea) { src = Q; dst = qinv; }
    else               { src = K; dst = kinv; row -= rowArea; }
    float4 v = *(const float4*)(src + row * D + lane * 4);
    float s = v.x*v.x + v.y*v.y + v.z*v.z + v.w*v.w;
    s += __shfl_xor(s, 1);
    s += __shfl_xor(s, 2);
    s += __shfl_xor(s, 4);
    s += __shfl_xor(s, 8);
    if (lane == 0) dst[row] = 1.0f / (sqrtf(s) + EPS);
}

// ---------------- Vt: V [bh][S][D] f32 -> Vt [bh][D][S] bf16 ----------------
__global__ __launch_bounds__(256) void vt_kernel(
    const float* __restrict__ V, unsigned short* __restrict__ Vt)
{
    __shared__ float tile[64 * 68];
    int bh = blockIdx.x >> 4;
    int k0 = (blockIdx.x & 15) * 64;
    int t = threadIdx.x;
    int r = t >> 2, cg = (t & 3) * 16;
    const float* Vb = V + ((size_t)bh * S + k0) * D;
    #pragma unroll
    for (int j = 0; j < 4; j++) {
        float4 v = *(const float4*)(Vb + r * D + cg + j * 4);
        *(float4*)(&tile[r * 68 + cg + j * 4]) = v;
    }
    __syncthreads();
    // thread writes Vt[d = r][k0 + cg .. +15]
    unsigned short wb[16];
    #pragma unroll
    for (int j = 0; j < 16; j++) wb[j] = f2bf(tile[(cg + j) * 68 + r]);
    unsigned short* dst = Vt + ((size_t)bh * D + r) * S + k0 + cg;
    *(uint4*)(dst)     = *(uint4*)(wb);
    *(uint4*)(dst + 8) = *(uint4*)(wb + 8);
}

// ---------------- GEMM1: u16 bin keys + packed-u16 LDS histogram ----------------
__global__ __launch_bounds__(256) void gemm1_kernel(
    const float* __restrict__ Q, const float* __restrict__ K,
    const float* __restrict__ qinv, const float* __restrict__ kinv,
    unsigned short* __restrict__ keys, unsigned* __restrict__ hist, int bh0)
{
    __shared__ float Qs[64 * 64];
    __shared__ float Kt[64 * 64];
    __shared__ unsigned hist_s[NWORDS];
    int tile = blockIdx.x & 255;
    int bhl  = blockIdx.x >> 8;
    int bh   = bh0 + bhl;
    int q0 = (tile >> 4) * 64, k0 = (tile & 15) * 64;
    int tid = threadIdx.x;

    #pragma unroll
    for (int i = tid; i < NWORDS / 4; i += 256) ((uint4*)hist_s)[i] = make_uint4(0,0,0,0);

    const float* Qb = Q + ((size_t)bh * S + q0) * D;
    const float* Kb = K + ((size_t)bh * S + k0) * D;
    #pragma unroll
    for (int r = 0; r < 4; r++) {
        int f = tid + r * 256;
        int row = f >> 4, c4 = f & 15;
        float4 v = *(const float4*)(Qb + row * D + c4 * 4);
        *(float4*)(&Qs[row * 64 + c4 * 4]) = v;
        float4 w = *(const float4*)(Kb + row * D + c4 * 4);
        int swz = row ^ ((c4 & 7) << 2);
        Kt[(c4*4+0) * 64 + swz] = w.x;
        Kt[(c4*4+1) * 64 + swz] = w.y;
        Kt[(c4*4+2) * 64 + swz] = w.z;
        Kt[(c4*4+3) * 64 + swz] = w.w;
    }
    __syncthreads();

    int tx = tid & 15, ty = tid >> 4;
    float acc[4][4] = {};
    #pragma unroll
    for (int d0 = 0; d0 < 16; d0++) {
        int kbase = (tx * 4) ^ ((d0 & 7) << 2);
        float4 b0 = *(const float4*)(&Kt[(d0*4+0)*64 + kbase]);
        float4 b1 = *(const float4*)(&Kt[(d0*4+1)*64 + kbase]);
        float4 b2 = *(const float4*)(&Kt[(d0*4+2)*64 + kbase]);
        float4 b3 = *(const float4*)(&Kt[(d0*4+3)*64 + kbase]);
        #pragma unroll
        for (int i = 0; i < 4; i++) {
            float4 a = *(const float4*)(&Qs[(ty*4+i)*64 + d0*4]);
            acc[i][0] += a.x*b0.x + a.y*b1.x + a.z*b2.x + a.w*b3.x;
            acc[i][1] += a.x*b0.y + a.y*b1.y + a.z*b2.y + a.w*b3.y;
            acc[i][2] += a.x*b0.z + a.y*b1.z + a.z*b2.z + a.w*b3.z;
            acc[i][3] += a.x*b0.w + a.y*b1.w + a.z*b2.w + a.w*b3.w;
        }
    }

    float kj[4];
    #pragma unroll
    for (int j = 0; j < 4; j++) kj[j] = kinv[(size_t)bh * S + k0 + tx*4 + j];
    #pragma unroll
    for (int i = 0; i < 4; i++) {
        float qi = qinv[(size_t)bh * S + q0 + ty*4 + i];
        int b0 = binof(acc[i][0] * qi * kj[0]);
        int b1 = binof(acc[i][1] * qi * kj[1]);
        int b2 = binof(acc[i][2] * qi * kj[2]);
        int b3 = binof(acc[i][3] * qi * kj[3]);
        ushort4 kv;
        kv.x = (unsigned short)b0; kv.y = (unsigned short)b1;
        kv.z = (unsigned short)b2; kv.w = (unsigned short)b3;
        *(ushort4*)(keys + ((size_t)bhl * S + q0 + ty*4 + i) * S + k0 + tx*4) = kv;
        atomicAdd(&hist_s[b0 >> 1], 1u << ((b0 & 1) << 4));
        atomicAdd(&hist_s[b1 >> 1], 1u << ((b1 & 1) << 4));
        atomicAdd(&hist_s[b2 >> 1], 1u << ((b2 & 1) << 4));
        atomicAdd(&hist_s[b3 >> 1], 1u << ((b3 & 1) << 4));
    }
    __syncthreads();

    unsigned* hb = hist + (size_t)bhl * NWORDS;
    #pragma unroll
    for (int i = tid; i < NWORDS; i += 256) {
        unsigned v = hist_s[i];
        if (v) atomicAdd(&hb[i], v);
    }
}

// ---------------- weight table: unpack + suffix scan + lgamma bin-average ----------------
__global__ __launch_bounds__(1024) void table_kernel(
    const unsigned* __restrict__ hist, float* __restrict__ wtab)
{
    __shared__ unsigned ssum[1024];
    int tid = threadIdx.x;
    const unsigned* h = hist + (size_t)blockIdx.x * NWORDS;
    float* wt = wtab + (size_t)blockIdx.x * NBINS;

    unsigned c[8];
    unsigned tot = 0;
    #pragma unroll
    for (int j = 0; j < 4; j++) {
        unsigned w = h[tid * 4 + j];
        c[2*j]   = w & 0xffffu;
        c[2*j+1] = w >> 16;
        tot += c[2*j] + c[2*j+1];
    }
    ssum[tid] = tot;
    __syncthreads();
    for (int ofs = 1; ofs < 1024; ofs <<= 1) {
        unsigned v = ssum[tid] + ((tid + ofs < 1024) ? ssum[tid + ofs] : 0u);
        __syncthreads();
        ssum[tid] = v;
        __syncthreads();
    }
    unsigned run = (tid < 1023) ? ssum[tid + 1] : 0u;

    const double ln_n = 13.862943611198906; // ln(1048576)
    #pragma unroll
    for (int i = 7; i >= 0; i--) {
        unsigned ci = c[i];
        float w = 0.0f;
        if (ci) {
            double b = (double)run, e = (double)(run + ci);
            double val = (double)ci * ln_n - (lgamma(e + 1.0) - lgamma(b + 1.0));
            w = (float)(val / (double)ci);
        }
        wt[tid * 8 + i] = w;
        run += ci;
    }
}

// ---------------- GEMM2 (MFMA bf16): out = (W/rowsum) @ V ----------------
// Per block: 64 q-rows x full D=64. Stage W-tile (keys -> gather -> bf16) into
// XOR-swizzled LDS, MFMA 16x16x32 against Vt fragments read straight from global.
__global__ __launch_bounds__(256) void gemm2_kernel(
    const unsigned short* __restrict__ keys, const float* __restrict__ Wtab,
    const unsigned short* __restrict__ Vt, float* __restrict__ out, int bh0)
{
    __shared__ float wt_s[NBINS];                         // 32 KB
    __shared__ __align__(16) unsigned short Ws[64 * 64];  // 8 KB bf16, XOR-swizzled
    __shared__ float rowsum_s[64];
    int bhl = blockIdx.x >> 4;
    int bh  = bh0 + bhl;
    int q0  = (blockIdx.x & 15) * 64;
    int t = threadIdx.x;

    const float* wtg = Wtab + (size_t)bhl * NBINS;
    #pragma unroll
    for (int i = t; i < NBINS / 4; i += 256)
        ((float4*)wt_s)[i] = ((const float4*)wtg)[i];

    int row = t >> 2;                 // staging: local q row 0..63
    int cg  = (t & 3) * 16;           // staging: col group base
    const unsigned short* kb = keys + ((size_t)bhl * S + q0 + row) * S + cg;
    const unsigned short* vb = Vt + (size_t)bh * D * S;

    int wv   = t >> 6;                // wave 0..3 -> q rows [wv*16, wv*16+16)
    int lane = t & 63;
    int col  = lane & 15;             // A row / C col
    int kgrp = lane >> 4;             // k group (8 elems each)
    floatx4 acc[4] = {};
    float rs = 0.f;

    unsigned sbyte = (unsigned)(row * 128 + cg * 2) ^ (unsigned)((row & 7) << 4);

    __syncthreads();                  // wt_s ready

    for (int k0 = 0; k0 < S; k0 += 64) {
        // gather 16 weights for this thread's 16 keys
        unsigned short kv[16];
        *(uint4*)(kv)     = *(const uint4*)(kb + k0);
        *(uint4*)(kv + 8) = *(const uint4*)(kb + k0 + 8);
        unsigned short wb[16];
        float part = 0.f;
        #pragma unroll
        for (int j = 0; j < 16; j++) {
            float w = wt_s[kv[j]];
            part += w;
            wb[j] = f2bf(w);
        }
        rs += part;
        __syncthreads();              // previous MFMA reads of Ws done
        *(uint4*)((char*)Ws + sbyte)        = *(uint4*)(wb);
        *(uint4*)((char*)Ws + (sbyte ^ 16)) = *(uint4*)(wb + 8);
        __syncthreads();              // Ws ready

        #pragma unroll
        for (int ks = 0; ks < 2; ks++) {
            int grow = wv * 16 + col;
            unsigned abyte = (unsigned)(grow * 128 + ks * 64 + kgrp * 16)
                           ^ (unsigned)((grow & 7) << 4);
            short8 a = *(const short8*)((const char*)Ws + abyte);
            #pragma unroll
            for (int n = 0; n < 4; n++) {
                short8 b = *(const short8*)(vb + (size_t)(n * 16 + col) * S
                                            + k0 + ks * 32 + kgrp * 8);
                acc[n] = __builtin_amdgcn_mfma_f32_16x16x32_bf16(a, b, acc[n], 0, 0, 0);
            }
        }
    }

    // rowsum: 4 staging threads per row -> reduce, publish
    rs += __shfl_xor(rs, 1);
    rs += __shfl_xor(rs, 2);
    if ((t & 3) == 0) rowsum_s[row] = rs;
    __syncthreads();

    #pragma unroll
    for (int n = 0; n < 4; n++) {
        #pragma unroll
        for (int r = 0; r < 4; r++) {
            int q = wv * 16 + kgrp * 4 + r;    // C row = (lane>>4)*4 + reg
            float inv = 1.0f / rowsum_s[q];
            out[((size_t)bh * S + q0 + q) * D + n * 16 + col] = acc[n][r] * inv;
        }
    }
}

extern "C" void kernel_launch(void* const* d_in, const int* in_sizes, int n_in,
                              void* d_out, int out_size, void* d_ws, size_t ws_size,
                              hipStream_t stream) {
    const float* Q = (const float*)d_in[0];
    const float* K = (const float*)d_in[1];
    const float* V = (const float*)d_in[2];
    float* out = (float*)d_out;

    char* w = (char*)d_ws;
    float* qinv = (float*)w;
    float* kinv = qinv + NBH * S;
    unsigned short* Vt = (unsigned short*)(w + (size_t)2 * NBH * S * sizeof(float));
    size_t off = (size_t)2 * NBH * S * sizeof(float) + (size_t)NBH * D * S * 2;
    // per-bh: packed hist + f32 weight table + u16 keys
    size_t per_bh = (size_t)NWORDS * 4 + (size_t)NBINS * 4 + (size_t)S * S * 2;
    long long avail = (long long)ws_size - (long long)off;
    int G = (int)(avail / (long long)per_bh);
    if (G > NBH) G = NBH;
    if (G < 1) G = 1;
    unsigned* hist = (unsigned*)(w + off);
    float* wtab = (float*)(w + off + (size_t)G * NWORDS * 4);
    unsigned short* keys = (unsigned short*)(w + off + (size_t)G * NWORDS * 4 + (size_t)G * NBINS * 4);

    norms_kernel<<<(2 * NBH * S) / 16, 256, 0, stream>>>(Q, K, qinv, kinv);
    vt_kernel<<<NBH * 16, 256, 0, stream>>>(V, Vt);

    for (int bh0 = 0; bh0 < NBH; bh0 += G) {
        int Gc = (NBH - bh0 < G) ? (NBH - bh0) : G;
        hipMemsetAsync(hist, 0, (size_t)Gc * NWORDS * 4, stream);
        gemm1_kernel<<<Gc * 256, 256, 0, stream>>>(Q, K, qinv, kinv, keys, hist, bh0);
        table_kernel<<<Gc, 1024, 0, stream>>>(hist, wtab);
        gemm2_kernel<<<Gc * 16, 256, 0, stream>>>(keys, wtab, Vt, out, bh0);
    }
}

// Round 5
// 255.131 us; speedup vs baseline: 19.2024x; 1.2599x over previous
//
#include <hip/hip_runtime.h>
#include <math.h>

#define S 1024
#define D 64
#define NBH 64
#define NBINS 8192
#define NWORDS (NBINS / 2)
#define EPS 1e-5f

typedef __attribute__((ext_vector_type(8))) short short8;
typedef __attribute__((ext_vector_type(4))) float floatx4;

__device__ __forceinline__ int binof(float sim) {
    int b = (int)((sim + 1.0f) * (NBINS / 2));
    return b < 0 ? 0 : (b > NBINS - 1 ? NBINS - 1 : b);
}

__device__ __forceinline__ unsigned short f2bf(float f) {   // RNE f32->bf16
    unsigned u = __float_as_uint(f);
    u += 0x7fffu + ((u >> 16) & 1u);
    return (unsigned short)(u >> 16);
}
__device__ __forceinline__ float bf2f(unsigned short h) {
    return __uint_as_float(((unsigned)h) << 16);
}

// ---------------- norms + hi/lo bf16 split for Q and K ----------------
// 16 lanes per row, 16 rows per 256-thread block.
__global__ __launch_bounds__(256) void norms_kernel(
    const float* __restrict__ Q, const float* __restrict__ K,
    float* __restrict__ qinv, float* __restrict__ kinv,
    unsigned short* __restrict__ Qhi, unsigned short* __restrict__ Qlo,
    unsigned short* __restrict__ Khi, unsigned short* __restrict__ Klo)
{
    int tid = threadIdx.x;
    int grp = tid >> 4, lane = tid & 15;
    long long rowArea = (long long)NBH * S;
    long long row = (long long)blockIdx.x * 16 + grp;
    const float* src; float* dst; unsigned short *dhi, *dlo;
    if (row < rowArea) { src = Q; dst = qinv; dhi = Qhi; dlo = Qlo; }
    else               { src = K; dst = kinv; dhi = Khi; dlo = Klo; row -= rowArea; }
    float4 v = *(const float4*)(src + row * D + lane * 4);
    float s = v.x*v.x + v.y*v.y + v.z*v.z + v.w*v.w;
    s += __shfl_xor(s, 1);
    s += __shfl_xor(s, 2);
    s += __shfl_xor(s, 4);
    s += __shfl_xor(s, 8);
    if (lane == 0) dst[row] = 1.0f / (sqrtf(s) + EPS);

    float f[4] = {v.x, v.y, v.z, v.w};
    unsigned short hi[4], lo[4];
    #pragma unroll
    for (int j = 0; j < 4; j++) {
        hi[j] = f2bf(f[j]);
        lo[j] = f2bf(f[j] - bf2f(hi[j]));
    }
    *(ushort4*)(dhi + row * D + lane * 4) = *(ushort4*)hi;
    *(ushort4*)(dlo + row * D + lane * 4) = *(ushort4*)lo;
}

// ---------------- Vt: V [bh][S][D] f32 -> Vt [bh][D][S] bf16 ----------------
__global__ __launch_bounds__(256) void vt_kernel(
    const float* __restrict__ V, unsigned short* __restrict__ Vt)
{
    __shared__ float tile[64 * 68];
    int bh = blockIdx.x >> 4;
    int k0 = (blockIdx.x & 15) * 64;
    int t = threadIdx.x;
    int r = t >> 2, cg = (t & 3) * 16;
    const float* Vb = V + ((size_t)bh * S + k0) * D;
    #pragma unroll
    for (int j = 0; j < 4; j++) {
        float4 v = *(const float4*)(Vb + r * D + cg + j * 4);
        *(float4*)(&tile[r * 68 + cg + j * 4]) = v;
    }
    __syncthreads();
    unsigned short wb[16];
    #pragma unroll
    for (int j = 0; j < 16; j++) wb[j] = f2bf(tile[(cg + j) * 68 + r]);
    unsigned short* dst = Vt + ((size_t)bh * D + r) * S + k0 + cg;
    *(uint4*)(dst)     = *(uint4*)(wb);
    *(uint4*)(dst + 8) = *(uint4*)(wb + 8);
}

// ---------------- GEMM1 (MFMA, compensated bf16): keys + LDS histogram ----------------
// 128q x 128k tile per 256-thread block; wave wv owns q-rows [wv*32, wv*32+32).
// score = (Qhi+Qlo)·(Khi+Klo) ~ hi·hi + hi·lo + lo·hi  (3 MFMAs, err ~2^-18)
__global__ __launch_bounds__(256) void gemm1_kernel(
    const unsigned short* __restrict__ Qhi, const unsigned short* __restrict__ Qlo,
    const unsigned short* __restrict__ Khi, const unsigned short* __restrict__ Klo,
    const float* __restrict__ qinv, const float* __restrict__ kinv,
    unsigned short* __restrict__ keys, unsigned* __restrict__ hist, int bh0)
{
    __shared__ unsigned hist_s[NWORDS];   // 16 KB packed u16 pairs
    int tile = blockIdx.x & 63;
    int bhl  = blockIdx.x >> 6;
    int bh   = bh0 + bhl;
    int q0 = (tile >> 3) * 128, k0 = (tile & 7) * 128;
    int t = threadIdx.x;

    #pragma unroll
    for (int i = t; i < NWORDS / 4; i += 256) ((uint4*)hist_s)[i] = make_uint4(0,0,0,0);

    int wv = t >> 6, lane = t & 63, col = lane & 15, kgrp = lane >> 4;
    const unsigned short* qhb = Qhi + ((size_t)bh * S + q0 + wv * 32) * D;
    const unsigned short* qlb = Qlo + ((size_t)bh * S + q0 + wv * 32) * D;
    const unsigned short* khb = Khi + ((size_t)bh * S + k0) * D;
    const unsigned short* klb = Klo + ((size_t)bh * S + k0) * D;

    floatx4 acc[2][8] = {};
    #pragma unroll
    for (int ks = 0; ks < 2; ks++) {
        int doff = ks * 32 + kgrp * 8;
        short8 ah[2], al[2];
        #pragma unroll
        for (int qs = 0; qs < 2; qs++) {
            ah[qs] = *(const short8*)(qhb + (qs * 16 + col) * D + doff);
            al[qs] = *(const short8*)(qlb + (qs * 16 + col) * D + doff);
        }
        #pragma unroll
        for (int n = 0; n < 8; n++) {
            short8 bh8 = *(const short8*)(khb + (n * 16 + col) * D + doff);
            short8 bl8 = *(const short8*)(klb + (n * 16 + col) * D + doff);
            #pragma unroll
            for (int qs = 0; qs < 2; qs++) {
                acc[qs][n] = __builtin_amdgcn_mfma_f32_16x16x32_bf16(ah[qs], bh8, acc[qs][n], 0, 0, 0);
                acc[qs][n] = __builtin_amdgcn_mfma_f32_16x16x32_bf16(ah[qs], bl8, acc[qs][n], 0, 0, 0);
                acc[qs][n] = __builtin_amdgcn_mfma_f32_16x16x32_bf16(al[qs], bh8, acc[qs][n], 0, 0, 0);
            }
        }
    }
    __syncthreads();   // hist_s zeroed before atomics

    float qv[2][4];
    #pragma unroll
    for (int qs = 0; qs < 2; qs++)
        #pragma unroll
        for (int r = 0; r < 4; r++)
            qv[qs][r] = qinv[(size_t)bh * S + q0 + wv * 32 + qs * 16 + kgrp * 4 + r];
    float kvv[8];
    #pragma unroll
    for (int n = 0; n < 8; n++)
        kvv[n] = kinv[(size_t)bh * S + k0 + n * 16 + col];

    unsigned short* kb = keys + ((size_t)bhl * S + q0 + wv * 32) * S + k0;
    #pragma unroll
    for (int qs = 0; qs < 2; qs++) {
        #pragma unroll
        for (int n = 0; n < 8; n++) {
            floatx4 a = acc[qs][n];
            #pragma unroll
            for (int r = 0; r < 4; r++) {
                float sc = a[r] * qv[qs][r] * kvv[n];
                int b = binof(sc);
                kb[(size_t)(qs * 16 + kgrp * 4 + r) * S + n * 16 + col] = (unsigned short)b;
                atomicAdd(&hist_s[b >> 1], 1u << ((b & 1) << 4));
            }
        }
    }
    __syncthreads();

    unsigned* hb = hist + (size_t)bhl * NWORDS;
    #pragma unroll
    for (int i = t; i < NWORDS; i += 256) {
        unsigned v = hist_s[i];
        if (v) atomicAdd(&hb[i], v);
    }
}

// ---------------- weight table: unpack + suffix scan + lgamma bin-average ----------------
__global__ __launch_bounds__(1024) void table_kernel(
    const unsigned* __restrict__ hist, float* __restrict__ wtab)
{
    __shared__ unsigned ssum[1024];
    int tid = threadIdx.x;
    const unsigned* h = hist + (size_t)blockIdx.x * NWORDS;
    float* wt = wtab + (size_t)blockIdx.x * NBINS;

    unsigned c[8];
    unsigned tot = 0;
    #pragma unroll
    for (int j = 0; j < 4; j++) {
        unsigned w = h[tid * 4 + j];
        c[2*j]   = w & 0xffffu;
        c[2*j+1] = w >> 16;
        tot += c[2*j] + c[2*j+1];
    }
    ssum[tid] = tot;
    __syncthreads();
    for (int ofs = 1; ofs < 1024; ofs <<= 1) {
        unsigned v = ssum[tid] + ((tid + ofs < 1024) ? ssum[tid + ofs] : 0u);
        __syncthreads();
        ssum[tid] = v;
        __syncthreads();
    }
    unsigned run = (tid < 1023) ? ssum[tid + 1] : 0u;

    const double ln_n = 13.862943611198906; // ln(1048576)
    #pragma unroll
    for (int i = 7; i >= 0; i--) {
        unsigned ci = c[i];
        float w = 0.0f;
        if (ci) {
            double b = (double)run, e = (double)(run + ci);
            double val = (double)ci * ln_n - (lgamma(e + 1.0) - lgamma(b + 1.0));
            w = (float)(val / (double)ci);
        }
        wt[tid * 8 + i] = w;
        run += ci;
    }
}

// ---------------- GEMM2 (MFMA bf16): out = (W/rowsum) @ V ----------------
__global__ __launch_bounds__(256) void gemm2_kernel(
    const unsigned short* __restrict__ keys, const float* __restrict__ Wtab,
    const unsigned short* __restrict__ Vt, float* __restrict__ out, int bh0)
{
    __shared__ float wt_s[NBINS];                         // 32 KB
    __shared__ __align__(16) unsigned short Ws[64 * 64];  // 8 KB bf16, XOR-swizzled
    __shared__ float rowsum_s[64];
    int bhl = blockIdx.x >> 4;
    int bh  = bh0 + bhl;
    int q0  = (blockIdx.x & 15) * 64;
    int t = threadIdx.x;

    const float* wtg = Wtab + (size_t)bhl * NBINS;
    #pragma unroll
    for (int i = t; i < NBINS / 4; i += 256)
        ((float4*)wt_s)[i] = ((const float4*)wtg)[i];

    int row = t >> 2;
    int cg  = (t & 3) * 16;
    const unsigned short* kb = keys + ((size_t)bhl * S + q0 + row) * S + cg;
    const unsigned short* vb = Vt + (size_t)bh * D * S;

    int wv   = t >> 6;
    int lane = t & 63;
    int col  = lane & 15;
    int kgrp = lane >> 4;
    floatx4 acc[4] = {};
    float rs = 0.f;

    unsigned sbyte = (unsigned)(row * 128 + cg * 2) ^ (unsigned)((row & 7) << 4);

    __syncthreads();

    for (int k0 = 0; k0 < S; k0 += 64) {
        unsigned short kv[16];
        *(uint4*)(kv)     = *(const uint4*)(kb + k0);
        *(uint4*)(kv + 8) = *(const uint4*)(kb + k0 + 8);
        unsigned short wb[16];
        float part = 0.f;
        #pragma unroll
        for (int j = 0; j < 16; j++) {
            float w = wt_s[kv[j]];
            part += w;
            wb[j] = f2bf(w);
        }
        rs += part;
        __syncthreads();
        *(uint4*)((char*)Ws + sbyte)        = *(uint4*)(wb);
        *(uint4*)((char*)Ws + (sbyte ^ 16)) = *(uint4*)(wb + 8);
        __syncthreads();

        #pragma unroll
        for (int ks = 0; ks < 2; ks++) {
            int grow = wv * 16 + col;
            unsigned abyte = (unsigned)(grow * 128 + ks * 64 + kgrp * 16)
                           ^ (unsigned)((grow & 7) << 4);
            short8 a = *(const short8*)((const char*)Ws + abyte);
            #pragma unroll
            for (int n = 0; n < 4; n++) {
                short8 b = *(const short8*)(vb + (size_t)(n * 16 + col) * S
                                            + k0 + ks * 32 + kgrp * 8);
                acc[n] = __builtin_amdgcn_mfma_f32_16x16x32_bf16(a, b, acc[n], 0, 0, 0);
            }
        }
    }

    rs += __shfl_xor(rs, 1);
    rs += __shfl_xor(rs, 2);
    if ((t & 3) == 0) rowsum_s[row] = rs;
    __syncthreads();

    #pragma unroll
    for (int n = 0; n < 4; n++) {
        #pragma unroll
        for (int r = 0; r < 4; r++) {
            int q = wv * 16 + kgrp * 4 + r;
            float inv = 1.0f / rowsum_s[q];
            out[((size_t)bh * S + q0 + q) * D + n * 16 + col] = acc[n][r] * inv;
        }
    }
}

extern "C" void kernel_launch(void* const* d_in, const int* in_sizes, int n_in,
                              void* d_out, int out_size, void* d_ws, size_t ws_size,
                              hipStream_t stream) {
    const float* Q = (const float*)d_in[0];
    const float* K = (const float*)d_in[1];
    const float* V = (const float*)d_in[2];
    float* out = (float*)d_out;

    char* w = (char*)d_ws;
    float* qinv = (float*)w;
    float* kinv = qinv + NBH * S;
    size_t off = (size_t)2 * NBH * S * sizeof(float);
    unsigned short* Qhi = (unsigned short*)(w + off); off += (size_t)NBH * S * D * 2;
    unsigned short* Qlo = (unsigned short*)(w + off); off += (size_t)NBH * S * D * 2;
    unsigned short* Khi = (unsigned short*)(w + off); off += (size_t)NBH * S * D * 2;
    unsigned short* Klo = (unsigned short*)(w + off); off += (size_t)NBH * S * D * 2;
    unsigned short* Vt  = (unsigned short*)(w + off); off += (size_t)NBH * D * S * 2;
    // per-bh: packed hist + f32 weight table + u16 keys
    size_t per_bh = (size_t)NWORDS * 4 + (size_t)NBINS * 4 + (size_t)S * S * 2;
    long long avail = (long long)ws_size - (long long)off;
    int G = (int)(avail / (long long)per_bh);
    if (G > NBH) G = NBH;
    if (G < 1) G = 1;
    unsigned* hist = (unsigned*)(w + off);
    float* wtab = (float*)(w + off + (size_t)G * NWORDS * 4);
    unsigned short* keys = (unsigned short*)(w + off + (size_t)G * NWORDS * 4 + (size_t)G * NBINS * 4);

    norms_kernel<<<(2 * NBH * S) / 16, 256, 0, stream>>>(Q, K, qinv, kinv, Qhi, Qlo, Khi, Klo);
    vt_kernel<<<NBH * 16, 256, 0, stream>>>(V, Vt);

    for (int bh0 = 0; bh0 < NBH; bh0 += G) {
        int Gc = (NBH - bh0 < G) ? (NBH - bh0) : G;
        hipMemsetAsync(hist, 0, (size_t)Gc * NWORDS * 4, stream);
        gemm1_kernel<<<Gc * 64, 256, 0, stream>>>(Qhi, Qlo, Khi, Klo, qinv, kinv, keys, hist, bh0);
        table_kernel<<<Gc, 1024, 0, stream>>>(hist, wtab);
        gemm2_kernel<<<Gc * 16, 256, 0, stream>>>(keys, wtab, Vt, out, bh0);
    }
}